// Round 1
// baseline (11435.279 us; speedup 1.0000x reference)
//
#include <hip/hip_runtime.h>
#include <math.h>

// Problem constants
#define BB 64
#define SS 64
#define VV 8
#define WW 256
#define DD 8
#define BS (BB*SS)        // 4096
#define BSV (BB*SS*VV)    // 32768

// ---------------------------------------------------------------------------
// Generic tiled fp32 GEMM: C[M,N] = act(A[M,K] @ B[K,N] + bias) + res
// 64x64 tile, 256 threads, 4x4 accum per thread, K-tile = 16.
// ---------------------------------------------------------------------------
__global__ __launch_bounds__(256) void gemm64(
    const float* __restrict__ A, const float* __restrict__ B,
    const float* __restrict__ bias, const float* __restrict__ res,
    float* __restrict__ C, int M, int K, int N, int relu)
{
    __shared__ float As[16][65];
    __shared__ float Bs[16][65];
    int tid  = threadIdx.x;
    int row0 = blockIdx.y * 64;
    int col0 = blockIdx.x * 64;
    int ty = tid >> 4, tx = tid & 15;
    float acc[4][4] = {};
    for (int kt = 0; kt < K; kt += 16) {
#pragma unroll
        for (int i = 0; i < 4; i++) {
            int e = tid + i * 256;
            int r = e >> 4, kk = e & 15;
            int gr = row0 + r, gk = kt + kk;
            As[kk][r] = (gr < M && gk < K) ? A[(size_t)gr * K + gk] : 0.f;
        }
#pragma unroll
        for (int i = 0; i < 4; i++) {
            int e = tid + i * 256;
            int kk = e >> 6, c = e & 63;
            int gk = kt + kk, gc = col0 + c;
            Bs[kk][c] = (gk < K && gc < N) ? B[(size_t)gk * N + gc] : 0.f;
        }
        __syncthreads();
#pragma unroll
        for (int kk = 0; kk < 16; kk++) {
            float a0[4], b0[4];
#pragma unroll
            for (int im = 0; im < 4; im++) a0[im] = As[kk][ty * 4 + im];
#pragma unroll
            for (int in = 0; in < 4; in++) b0[in] = Bs[kk][tx * 4 + in];
#pragma unroll
            for (int im = 0; im < 4; im++)
#pragma unroll
                for (int in = 0; in < 4; in++)
                    acc[im][in] += a0[im] * b0[in];
        }
        __syncthreads();
    }
#pragma unroll
    for (int im = 0; im < 4; im++) {
        int r = row0 + ty * 4 + im;
        if (r >= M) continue;
#pragma unroll
        for (int in = 0; in < 4; in++) {
            int c = col0 + tx * 4 + in;
            if (c >= N) continue;
            float v = acc[im][in];
            if (bias) v += bias[c];
            if (relu) v = fmaxf(v, 0.f);
            if (res)  v += res[(size_t)r * N + c];
            C[(size_t)r * N + c] = v;
        }
    }
}

// ---------------------------------------------------------------------------
// LayerNorm over last dim (256). One block (256 threads) per row.
// ---------------------------------------------------------------------------
__global__ __launch_bounds__(256) void lnorm(
    const float* __restrict__ in, const float* __restrict__ g,
    const float* __restrict__ b, float* __restrict__ out, float eps)
{
    int row = blockIdx.x, t = threadIdx.x;
    float x = in[row * WW + t];
    __shared__ float red[256];
    red[t] = x;
    __syncthreads();
    for (int s = 128; s > 0; s >>= 1) { if (t < s) red[t] += red[t + s]; __syncthreads(); }
    float m = red[0] * (1.f / 256.f);
    __syncthreads();
    float d = x - m;
    red[t] = d * d;
    __syncthreads();
    for (int s = 128; s > 0; s >>= 1) { if (t < s) red[t] += red[t + s]; __syncthreads(); }
    float var = red[0] * (1.f / 256.f);
    out[row * WW + t] = d / sqrtf(var + eps) * g[t] + b[t];
}

// Positional encoding for pts: [4096,3] -> [4096,63]  (x, sin(x*2^k) k=0..9, cos)
__global__ void penc_pts(const float* __restrict__ pts, float* __restrict__ out)
{
    int bs = blockIdx.x * blockDim.x + threadIdx.x;
    if (bs >= BS) return;
    float x0 = pts[bs * 3 + 0], x1 = pts[bs * 3 + 1], x2 = pts[bs * 3 + 2];
    float xs[3] = {x0, x1, x2};
    float* o = out + (size_t)bs * 63;
    o[0] = x0; o[1] = x1; o[2] = x2;
    for (int d = 0; d < 3; d++) {
        float f = 1.f;
        for (int k = 0; k < 10; k++) {
            float ang = xs[d] * f;
            o[3 + d * 10 + k]  = sinf(ang);
            o[33 + d * 10 + k] = cosf(ang);
            f *= 2.f;
        }
    }
}

// Positional encoding for normalized view dirs: [64,3] -> [64,27]
__global__ void penc_views(const float* __restrict__ ray_d, float* __restrict__ out)
{
    int b = threadIdx.x;
    if (b >= BB) return;
    float x = ray_d[b * 3], y = ray_d[b * 3 + 1], z = ray_d[b * 3 + 2];
    float inv = 1.f / sqrtf(x * x + y * y + z * z);
    float v[3] = {x * inv, y * inv, z * inv};
    float* o = out + (size_t)b * 27;
    o[0] = v[0]; o[1] = v[1]; o[2] = v[2];
    for (int d = 0; d < 3; d++) {
        float f = 1.f;
        for (int k = 0; k < 4; k++) {
            float ang = v[d] * f;
            o[3 + d * 4 + k]  = sinf(ang);
            o[15 + d * 4 + k] = cosf(ang);
            f *= 2.f;
        }
    }
}

// fq[bs,w] = max_v rgbf[bs,v,w]
__global__ void vmax(const float* __restrict__ rgbf, float* __restrict__ fq)
{
    int idx = blockIdx.x * 256 + threadIdx.x;   // 4096*256 elements
    int bs = idx >> 8, w = idx & 255;
    float m = -1e30f;
    for (int v = 0; v < VV; v++) m = fmaxf(m, rgbf[((size_t)(bs * VV + v)) * WW + w]);
    fq[idx] = m;
}

// kb <- kb - q(bcast over V) + pos ;  vb <- vb + pos
__global__ void aprep(float* __restrict__ kb, float* __restrict__ vb,
                      const float* __restrict__ pos, const float* __restrict__ q)
{
    int idx = blockIdx.x * 256 + threadIdx.x;   // 32768*256 elements
    int w = idx & 255;
    int bs = idx >> 11;                          // /(V*W)
    float p = pos[idx];
    kb[idx] = kb[idx] - q[(bs << 8) + w] + p;
    vb[idx] = vb[idx] + p;
}

// masked softmax over V + weighted sum:  o[bs,w] = sum_v softmax_v(a)[v] * vpos[v]
__global__ __launch_bounds__(256) void smax(
    const float* __restrict__ a, const float* __restrict__ vpos,
    const int* __restrict__ mask, float* __restrict__ o)
{
    int bs = blockIdx.x, w = threadIdx.x;
    __shared__ int m[VV];
    if (w < VV) m[w] = mask[bs * VV + w];
    __syncthreads();
    float x[VV]; float mx = -1e30f;
    for (int v = 0; v < VV; v++) {
        float t = a[((size_t)(bs * VV + v)) * WW + w];
        t = (m[v] == 0) ? -1e9f : t;
        x[v] = t; mx = fmaxf(mx, t);
    }
    float s = 0.f;
    for (int v = 0; v < VV; v++) { x[v] = expf(x[v] - mx); s += x[v]; }
    float inv = 1.f / s;
    float acc = 0.f;
    for (int v = 0; v < VV; v++) acc += x[v] * inv * vpos[((size_t)(bs * VV + v)) * WW + w];
    o[bs * WW + w] = acc;
}

// build cat[4096,346] = [fq(256) | input_pts(63) | input_views(27, per-b)]
__global__ void catk(const float* __restrict__ fq, const float* __restrict__ ipts,
                     const float* __restrict__ ivw, float* __restrict__ cat, int total)
{
    int idx = blockIdx.x * 256 + threadIdx.x;
    if (idx >= total) return;
    int bs = idx / 346, j = idx % 346;
    float v;
    if (j < 256)      v = fq[bs * WW + j];
    else if (j < 319) v = ipts[bs * 63 + (j - 256)];
    else              v = ivw[(bs >> 6) * 27 + (j - 319)];
    cat[idx] = v;
}

// Self-attention: one block per (b,h). S=64, dh=64, scale=1/8.
__global__ __launch_bounds__(256) void attnk(
    const float* __restrict__ Q, const float* __restrict__ K,
    const float* __restrict__ Vv, float* __restrict__ O)
{
    __shared__ float qs[64][65];
    __shared__ float ks[64][65];
    __shared__ float sc[64][65];
    int b = blockIdx.x >> 2, h = blockIdx.x & 3, t = threadIdx.x;
#pragma unroll
    for (int i = 0; i < 16; i++) {
        int e = t + i * 256; int s = e >> 6, d = e & 63;
        int g = (b * SS + s) * WW + h * 64 + d;
        qs[s][d] = Q[g]; ks[s][d] = K[g];
    }
    __syncthreads();
    int qr = t >> 2, c0 = (t & 3) << 4;
    float tmp[16];
#pragma unroll
    for (int i = 0; i < 16; i++) {
        int c = c0 + i; float acc = 0.f;
        for (int k = 0; k < 64; k++) acc += qs[qr][k] * ks[c][k];
        tmp[i] = acc * 0.125f;
    }
    __syncthreads();   // all reads of ks done
#pragma unroll
    for (int i = 0; i < 16; i++) sc[qr][c0 + i] = tmp[i];
    // reload V into ks
#pragma unroll
    for (int i = 0; i < 16; i++) {
        int e = t + i * 256; int s = e >> 6, d = e & 63;
        ks[s][d] = Vv[(b * SS + s) * WW + h * 64 + d];
    }
    __syncthreads();
    if (t < 64) {
        float mx = -1e30f;
        for (int c = 0; c < 64; c++) mx = fmaxf(mx, sc[t][c]);
        float sum = 0.f;
        for (int c = 0; c < 64; c++) { float e = expf(sc[t][c] - mx); sc[t][c] = e; sum += e; }
        float inv = 1.f / sum;
        for (int c = 0; c < 64; c++) sc[t][c] *= inv;
    }
    __syncthreads();
#pragma unroll
    for (int i = 0; i < 16; i++) {
        int d = c0 + i; float acc = 0.f;
        for (int k = 0; k < 64; k++) acc += sc[qr][k] * ks[k][d];
        O[(b * SS + qr) * WW + h * 64 + d] = acc;
    }
}

// final head: mean over S then [256]x[256,3] matvec + bias
__global__ __launch_bounds__(256) void headk(
    const float* __restrict__ h, const float* __restrict__ ow,
    const float* __restrict__ ob, float* __restrict__ out)
{
    int b = blockIdx.x, t = threadIdx.x;
    float acc = 0.f;
    for (int s = 0; s < SS; s++) acc += h[((size_t)(b * SS + s)) * WW + t];
    __shared__ float mean[256];
    mean[t] = acc * (1.f / 64.f);
    __syncthreads();
    if (t < 3) {
        float o = ob[t];
        for (int w = 0; w < WW; w++) o += mean[w] * ow[w * 3 + t];
        out[b * 3 + t] = o;
    }
}

// ---------------------------------------------------------------------------
static inline void gemm(hipStream_t st, const float* A, const float* B,
                        const float* bias, const float* res, float* C,
                        int M, int K, int N, int relu)
{
    dim3 g((N + 63) / 64, (M + 63) / 64);
    gemm64<<<g, 256, 0, st>>>(A, B, bias, res, C, M, K, N, relu);
}

extern "C" void kernel_launch(void* const* d_in, const int* in_sizes, int n_in,
                              void* d_out, int out_size, void* d_ws, size_t ws_size,
                              hipStream_t stream)
{
    const float* rgb_feat   = (const float*)d_in[0];
    const float* ray_diff   = (const float*)d_in[1];
    const int*   maskp      = (const int*)d_in[2];
    const float* pts        = (const float*)d_in[3];
    const float* ray_d      = (const float*)d_in[4];
    const float* rgbfeat_w1 = (const float*)d_in[5];
    const float* rgbfeat_b1 = (const float*)d_in[6];
    const float* rgbfeat_w2 = (const float*)d_in[7];
    const float* rgbfeat_b2 = (const float*)d_in[8];
    const float* c_ln_g = (const float*)d_in[9];
    const float* c_ln_b = (const float*)d_in[10];
    const float* c_qw   = (const float*)d_in[11];
    const float* c_kw   = (const float*)d_in[12];
    const float* c_vw   = (const float*)d_in[13];
    const float* c_pw1  = (const float*)d_in[14];
    const float* c_pb1  = (const float*)d_in[15];
    const float* c_pw2  = (const float*)d_in[16];
    const float* c_pb2  = (const float*)d_in[17];
    const float* c_aw1  = (const float*)d_in[18];
    const float* c_ab1  = (const float*)d_in[19];
    const float* c_aw2  = (const float*)d_in[20];
    const float* c_ab2  = (const float*)d_in[21];
    const float* c_ow   = (const float*)d_in[22];
    const float* c_ob   = (const float*)d_in[23];
    const float* c_fg   = (const float*)d_in[24];
    const float* c_fb   = (const float*)d_in[25];
    const float* c_fw1  = (const float*)d_in[26];
    const float* c_fb1  = (const float*)d_in[27];
    const float* c_fw2  = (const float*)d_in[28];
    const float* c_fb2  = (const float*)d_in[29];
    const float* s_ln_g = (const float*)d_in[30];
    const float* s_ln_b = (const float*)d_in[31];
    const float* s_qw   = (const float*)d_in[32];
    const float* s_kw   = (const float*)d_in[33];
    const float* s_vw   = (const float*)d_in[34];
    const float* s_ow   = (const float*)d_in[35];
    const float* s_ob   = (const float*)d_in[36];
    const float* s_fg   = (const float*)d_in[37];
    const float* s_fb   = (const float*)d_in[38];
    const float* s_fw1  = (const float*)d_in[39];
    const float* s_fb1  = (const float*)d_in[40];
    const float* s_fw2  = (const float*)d_in[41];
    const float* s_fb2  = (const float*)d_in[42];
    const float* q_w1   = (const float*)d_in[43];
    const float* q_b1   = (const float*)d_in[44];
    const float* q_w2   = (const float*)d_in[45];
    const float* q_b2   = (const float*)d_in[46];
    const float* norm_g = (const float*)d_in[47];
    const float* norm_b = (const float*)d_in[48];
    const float* out_w  = (const float*)d_in[49];
    const float* out_b  = (const float*)d_in[50];
    float* out = (float*)d_out;
    float* ws  = (float*)d_ws;

    // Workspace layout (floats)
    size_t off = 0;
    float* rgbf = ws + off; off += (size_t)BSV * WW;   // 8.39M
    float* kb   = ws + off; off += (size_t)BSV * WW;   // k / a_in
    float* vb   = ws + off; off += (size_t)BSV * WW;   // v / v+pos
    float* pb   = ws + off; off += (size_t)BSV * WW;   // pos / a_out
    float* ph   = ws + off; off += (size_t)BSV * 32;   // pos/a hidden
    float* ffh  = ws + off; off += (size_t)BS * 1024;  // FFN hidden
    float* fq   = ws + off; off += (size_t)BS * WW;
    float* xq   = ws + off; off += (size_t)BS * WW;
    float* qb   = ws + off; off += (size_t)BS * WW;
    float* ob   = ws + off; off += (size_t)BS * WW;    // o_pre
    float* hb   = ws + off; off += (size_t)BS * WW;
    float* cat  = ws + off; off += (size_t)BS * 346;
    float* ipts = ws + off; off += (size_t)BS * 63;
    float* ivw  = ws + off; off += (size_t)BB * 27;

    // ---- preamble ----
    penc_pts<<<(BS + 255) / 256, 256, 0, stream>>>(pts, ipts);
    penc_views<<<1, 64, 0, stream>>>(ray_d, ivw);
    gemm(stream, rgb_feat, rgbfeat_w1, rgbfeat_b1, nullptr, kb, BSV, 35, WW, 1);
    gemm(stream, kb, rgbfeat_w2, rgbfeat_b2, nullptr, rgbf, BSV, WW, WW, 0);
    vmax<<<BS, 256, 0, stream>>>(rgbf, fq);

    for (int i = 0; i < DD; i++) {
        // ---- cross transformer ----
        lnorm<<<BS, 256, 0, stream>>>(fq, c_ln_g + i * WW, c_ln_b + i * WW, xq, 1e-6f);
        gemm(stream, xq, c_qw + (size_t)i * WW * WW, nullptr, nullptr, qb, BS, WW, WW, 0);
        gemm(stream, rgbf, c_kw + (size_t)i * WW * WW, nullptr, nullptr, kb, BSV, WW, WW, 0);
        gemm(stream, rgbf, c_vw + (size_t)i * WW * WW, nullptr, nullptr, vb, BSV, WW, WW, 0);
        gemm(stream, ray_diff, c_pw1 + i * 128, c_pb1 + i * 32, nullptr, ph, BSV, 4, 32, 1);
        gemm(stream, ph, c_pw2 + i * 8192, c_pb2 + i * WW, nullptr, pb, BSV, 32, WW, 0);
        aprep<<<BSV, 256, 0, stream>>>(kb, vb, pb, qb);           // kb=a_in, vb=v+pos, pb free
        gemm(stream, kb, c_aw1 + i * 8192, c_ab1 + i * 32, nullptr, ph, BSV, WW, 32, 1);
        gemm(stream, ph, c_aw2 + i * 8192, c_ab2 + i * WW, nullptr, pb, BSV, 32, WW, 0);
        smax<<<BS, 256, 0, stream>>>(pb, vb, maskp, ob);
        gemm(stream, ob, c_ow + (size_t)i * WW * WW, c_ob + i * WW, fq, fq, BS, WW, WW, 0);
        lnorm<<<BS, 256, 0, stream>>>(fq, c_fg + i * WW, c_fb + i * WW, hb, 1e-6f);
        gemm(stream, hb, c_fw1 + (size_t)i * WW * 1024, c_fb1 + i * 1024, nullptr, ffh, BS, WW, 1024, 1);
        gemm(stream, ffh, c_fw2 + (size_t)i * 1024 * WW, c_fb2 + i * WW, fq, fq, BS, 1024, WW, 0);

        // ---- q_fc on even layers ----
        if ((i & 1) == 0) {
            int j = i >> 1;
            catk<<<(BS * 346 + 255) / 256, 256, 0, stream>>>(fq, ipts, ivw, cat, BS * 346);
            gemm(stream, cat, q_w1 + (size_t)j * 346 * WW, q_b1 + j * WW, nullptr, hb, BS, 346, WW, 1);
            gemm(stream, hb, q_w2 + (size_t)j * WW * WW, q_b2 + j * WW, nullptr, fq, BS, WW, WW, 0);
        }

        // ---- self transformer ----
        lnorm<<<BS, 256, 0, stream>>>(fq, s_ln_g + i * WW, s_ln_b + i * WW, xq, 1e-6f);
        gemm(stream, xq, s_qw + (size_t)i * WW * WW, nullptr, nullptr, qb, BS, WW, WW, 0);
        gemm(stream, xq, s_kw + (size_t)i * WW * WW, nullptr, nullptr, kb, BS, WW, WW, 0);
        gemm(stream, xq, s_vw + (size_t)i * WW * WW, nullptr, nullptr, vb, BS, WW, WW, 0);
        attnk<<<BB * 4, 256, 0, stream>>>(qb, kb, vb, ob);
        gemm(stream, ob, s_ow + (size_t)i * WW * WW, s_ob + i * WW, fq, fq, BS, WW, WW, 0);
        lnorm<<<BS, 256, 0, stream>>>(fq, s_fg + i * WW, s_fb + i * WW, hb, 1e-6f);
        gemm(stream, hb, s_fw1 + (size_t)i * WW * 1024, s_fb1 + i * 1024, nullptr, ffh, BS, WW, 1024, 1);
        gemm(stream, ffh, s_fw2 + (size_t)i * 1024 * WW, s_fb2 + i * WW, fq, fq, BS, 1024, WW, 0);
    }

    // ---- final norm + head ----
    lnorm<<<BS, 256, 0, stream>>>(fq, norm_g, norm_b, hb, 1e-5f);
    headk<<<BB, 256, 0, stream>>>(hb, out_w, out_b, out);
}

// Round 2
// 2656.724 us; speedup vs baseline: 4.3043x; 4.3043x over previous
//
#include <hip/hip_runtime.h>
#include <hip/hip_bf16.h>
#include <math.h>

#define BB 64
#define SS 64
#define VV 8
#define WW 256
#define DD 8
#define BS (BB*SS)        // 4096
#define BSV (BB*SS*VV)    // 32768

typedef __attribute__((ext_vector_type(8))) short s8v;
typedef __attribute__((ext_vector_type(4))) float f4v;

__device__ __forceinline__ short f2b(float f) {
    __hip_bfloat16 h = __float2bfloat16(f);
    return *reinterpret_cast<short*>(&h);
}
__device__ __forceinline__ float b2f(short s) {
    __hip_bfloat16 h = *reinterpret_cast<__hip_bfloat16*>(&s);
    return __bfloat162float(h);
}

// ---------------------------------------------------------------------------
// bf16 MFMA GEMM: C[M,N] = act(A[M,K] @ B[K,N] + bias) (+ res)
// A: bf16 [M,K] row-major. Bt: bf16 [N,K] (pre-transposed weights).
// 256 threads (4 waves). Tile TM x TN, BK=32, 16x16x32 MFMA.
// Wave w covers WM x WN; waves arranged (TM/WM) x (TN/WN).
// OUTBF: write bf16 (Cb) else fp32 (Cf, with optional fp32 residual).
// ---------------------------------------------------------------------------
template<int TM, int TN, int WM, int WN, bool OUTBF>
__global__ __launch_bounds__(256) void gemm_mfma(
    const short* __restrict__ A, const short* __restrict__ Bt,
    const float* __restrict__ bias, const float* __restrict__ res,
    float* __restrict__ Cf, short* __restrict__ Cb,
    int M, int N, int K, int relu)
{
    constexpr int MT  = WM / 16;
    constexpr int NT  = WN / 16;
    constexpr int RWN = TN / WN;
    __shared__ __align__(16) short As[TM * 32];
    __shared__ __align__(16) short Bs[TN * 32];
    int tid = threadIdx.x;
    int m0 = blockIdx.y * TM, n0 = blockIdx.x * TN;
    int lane = tid & 63, w = tid >> 6;
    int lm = lane & 15, lq = lane >> 4;
    int wm = (w / RWN) * WM, wn = (w % RWN) * WN;
    f4v acc[MT][NT];
#pragma unroll
    for (int i = 0; i < MT; i++)
#pragma unroll
        for (int j = 0; j < NT; j++) acc[i][j] = (f4v){0.f, 0.f, 0.f, 0.f};

    for (int k0 = 0; k0 < K; k0 += 32) {
        for (int c = tid; c < TM * 4; c += 256) {
            int r = c >> 2, kc = (c & 3) << 3;
            *(s8v*)&As[(r << 5) + kc] = *(const s8v*)&A[(size_t)(m0 + r) * K + k0 + kc];
        }
        for (int c = tid; c < TN * 4; c += 256) {
            int r = c >> 2, kc = (c & 3) << 3;
            *(s8v*)&Bs[(r << 5) + kc] = *(const s8v*)&Bt[(size_t)(n0 + r) * K + k0 + kc];
        }
        __syncthreads();
        s8v af[MT], bfv[NT];
#pragma unroll
        for (int i = 0; i < MT; i++)
            af[i] = *(const s8v*)&As[(wm + i * 16 + lm) * 32 + lq * 8];
#pragma unroll
        for (int j = 0; j < NT; j++)
            bfv[j] = *(const s8v*)&Bs[(wn + j * 16 + lm) * 32 + lq * 8];
#pragma unroll
        for (int i = 0; i < MT; i++)
#pragma unroll
            for (int j = 0; j < NT; j++)
                acc[i][j] = __builtin_amdgcn_mfma_f32_16x16x32_bf16(af[i], bfv[j], acc[i][j], 0, 0, 0);
        __syncthreads();
    }
    // Epilogue: C/D layout col=lane&15, row=quad*4+reg
#pragma unroll
    for (int i = 0; i < MT; i++) {
        int row = m0 + wm + i * 16 + lq * 4;
#pragma unroll
        for (int j = 0; j < NT; j++) {
            int col = n0 + wn + j * 16 + lm;
            float bv = bias ? bias[col] : 0.f;
#pragma unroll
            for (int r = 0; r < 4; r++) {
                float v = acc[i][j][r] + bv;
                if (relu) v = fmaxf(v, 0.f);
                size_t idx = (size_t)(row + r) * N + col;
                if (OUTBF) {
                    Cb[idx] = f2b(v);
                } else {
                    if (res) v += res[idx];
                    Cf[idx] = v;
                }
            }
        }
    }
}

// ---------------------------------------------------------------------------
// Weight convert+transpose: W fp32 [K,N] (per-z stride zi) -> Wt bf16 [N,Kpad]
// (per-z stride zo), zero-padded for k >= K. Block (32,8).
// ---------------------------------------------------------------------------
__global__ void wconv(const float* __restrict__ W, short* __restrict__ Wt,
                      int K, int N, int Kpad, int zi, int zo)
{
    __shared__ float t[32][33];
    int z = blockIdx.z;
    W  += (size_t)z * zi;
    Wt += (size_t)z * zo;
    int n0 = blockIdx.x * 32, k0 = blockIdx.y * 32;
    int tx = threadIdx.x, ty = threadIdx.y;
#pragma unroll
    for (int i = 0; i < 4; i++) {
        int k = k0 + ty + i * 8;
        t[ty + i * 8][tx] = (k < K) ? W[(size_t)k * N + n0 + tx] : 0.f;
    }
    __syncthreads();
#pragma unroll
    for (int i = 0; i < 4; i++) {
        int n = n0 + ty + i * 8;
        Wt[(size_t)n * Kpad + k0 + tx] = f2b(t[tx][ty + i * 8]);
    }
}

// rgb_feat fp32 [32768,35] -> bf16 [32768,64] zero-padded
__global__ void rgbconv(const float* __restrict__ x, short* __restrict__ o)
{
    int idx = blockIdx.x * 256 + threadIdx.x;
    int row = idx >> 6, col = idx & 63;
    o[idx] = f2b(col < 35 ? x[row * 35 + col] : 0.f);
}

// LayerNorm over 256, fp32 in -> bf16 out
__global__ __launch_bounds__(256) void lnormB(
    const float* __restrict__ in, const float* __restrict__ g,
    const float* __restrict__ b, short* __restrict__ out, float eps)
{
    int row = blockIdx.x, t = threadIdx.x;
    float x = in[(size_t)row * WW + t];
    __shared__ float red[256];
    red[t] = x;
    __syncthreads();
    for (int s = 128; s > 0; s >>= 1) { if (t < s) red[t] += red[t + s]; __syncthreads(); }
    float m = red[0] * (1.f / 256.f);
    __syncthreads();
    float d = x - m;
    red[t] = d * d;
    __syncthreads();
    for (int s = 128; s > 0; s >>= 1) { if (t < s) red[t] += red[t + s]; __syncthreads(); }
    float var = red[0] * (1.f / 256.f);
    out[(size_t)row * WW + t] = f2b(d / sqrtf(var + eps) * g[t] + b[t]);
}

__global__ void penc_pts(const float* __restrict__ pts, float* __restrict__ out)
{
    int bs = blockIdx.x * blockDim.x + threadIdx.x;
    if (bs >= BS) return;
    float xs[3] = {pts[bs * 3], pts[bs * 3 + 1], pts[bs * 3 + 2]};
    float* o = out + (size_t)bs * 63;
    o[0] = xs[0]; o[1] = xs[1]; o[2] = xs[2];
    for (int d = 0; d < 3; d++) {
        float f = 1.f;
        for (int k = 0; k < 10; k++) {
            float ang = xs[d] * f;
            o[3 + d * 10 + k]  = sinf(ang);
            o[33 + d * 10 + k] = cosf(ang);
            f *= 2.f;
        }
    }
}

__global__ void penc_views(const float* __restrict__ ray_d, float* __restrict__ out)
{
    int b = threadIdx.x;
    if (b >= BB) return;
    float x = ray_d[b * 3], y = ray_d[b * 3 + 1], z = ray_d[b * 3 + 2];
    float inv = 1.f / sqrtf(x * x + y * y + z * z);
    float v[3] = {x * inv, y * inv, z * inv};
    float* o = out + (size_t)b * 27;
    o[0] = v[0]; o[1] = v[1]; o[2] = v[2];
    for (int d = 0; d < 3; d++) {
        float f = 1.f;
        for (int k = 0; k < 4; k++) {
            float ang = v[d] * f;
            o[3 + d * 4 + k]  = sinf(ang);
            o[15 + d * 4 + k] = cosf(ang);
            f *= 2.f;
        }
    }
}

// fq[bs,w] = max_v rgbf_bf16[bs,v,w]
__global__ void vmax(const short* __restrict__ rgbf, float* __restrict__ fq)
{
    int idx = blockIdx.x * 256 + threadIdx.x;
    int bs = idx >> 8, w = idx & 255;
    float m = -1e30f;
    for (int v = 0; v < VV; v++) m = fmaxf(m, b2f(rgbf[((size_t)(bs * VV + v)) * WW + w]));
    fq[idx] = m;
}

// Fused pos-MLP + aprep: pos = relu(rd@pw1+pb1)@pw2+pb2 (fp32);
// a_in = bf16(k - q + pos); vpos = bf16(v + pos).  kv packed bf16 [row][512].
__global__ __launch_bounds__(256) void posprep(
    const float* __restrict__ rdiff, const float* __restrict__ pw1,
    const float* __restrict__ pb1, const float* __restrict__ pw2,
    const float* __restrict__ pb2, const short* __restrict__ kv,
    const float* __restrict__ q, short* __restrict__ a_in,
    short* __restrict__ vpos)
{
    int row = blockIdx.x, t = threadIdx.x;
    __shared__ float h[32];
    __shared__ float rd[4];
    if (t < 4) rd[t] = rdiff[row * 4 + t];
    __syncthreads();
    if (t < 32) {
        float a = pb1[t];
        for (int c = 0; c < 4; c++) a += rd[c] * pw1[c * 32 + t];
        h[t] = fmaxf(a, 0.f);
    }
    __syncthreads();
    float p = pb2[t];
    for (int j = 0; j < 32; j++) p += h[j] * pw2[j * 256 + t];
    int bs = row >> 3;
    float kk = b2f(kv[(size_t)row * 512 + t]);
    float vv = b2f(kv[(size_t)row * 512 + 256 + t]);
    a_in[(size_t)row * 256 + t] = f2b(kk - q[bs * 256 + t] + p);
    vpos[(size_t)row * 256 + t] = f2b(vv + p);
}

// masked softmax over V + weighted sum; a fp32, vpos bf16, out bf16
__global__ __launch_bounds__(256) void smax(
    const float* __restrict__ a, const short* __restrict__ vpos,
    const int* __restrict__ mask, short* __restrict__ o)
{
    int bs = blockIdx.x, w = threadIdx.x;
    __shared__ int m[VV];
    if (w < VV) m[w] = mask[bs * VV + w];
    __syncthreads();
    float x[VV]; float mx = -1e30f;
    for (int v = 0; v < VV; v++) {
        float t = a[((size_t)(bs * VV + v)) * WW + w];
        t = (m[v] == 0) ? -1e9f : t;
        x[v] = t; mx = fmaxf(mx, t);
    }
    float s = 0.f;
    for (int v = 0; v < VV; v++) { x[v] = expf(x[v] - mx); s += x[v]; }
    float inv = 1.f / s;
    float acc = 0.f;
    for (int v = 0; v < VV; v++) acc += x[v] * inv * b2f(vpos[((size_t)(bs * VV + v)) * WW + w]);
    o[(size_t)bs * WW + w] = f2b(acc);
}

// cat bf16 [4096,384] = [fq(256) | ipts(63) | ivw(27) | zeros(38)]
__global__ void catk(const float* __restrict__ fq, const float* __restrict__ ipts,
                     const float* __restrict__ ivw, short* __restrict__ cat)
{
    int idx = blockIdx.x * 256 + threadIdx.x;
    int bs = idx / 384, j = idx - bs * 384;
    float v;
    if (j < 256)      v = fq[(size_t)bs * WW + j];
    else if (j < 319) v = ipts[bs * 63 + (j - 256)];
    else if (j < 346) v = ivw[(bs >> 6) * 27 + (j - 319)];
    else              v = 0.f;
    cat[idx] = f2b(v);
}

// Self-attention, packed bf16 QKV [4096,768] (q|k|v), one block per (b,h)
__global__ __launch_bounds__(256) void attnk(
    const short* __restrict__ QKV, short* __restrict__ O)
{
    __shared__ float qs[64][65];
    __shared__ float ks[64][65];
    __shared__ float sc[64][65];
    int b = blockIdx.x >> 2, h = blockIdx.x & 3, t = threadIdx.x;
#pragma unroll
    for (int i = 0; i < 16; i++) {
        int e = t + i * 256; int s = e >> 6, d = e & 63;
        size_t g = (size_t)(b * SS + s) * 768 + h * 64 + d;
        qs[s][d] = b2f(QKV[g]); ks[s][d] = b2f(QKV[g + 256]);
    }
    __syncthreads();
    int qr = t >> 2, c0 = (t & 3) << 4;
    float tmp[16];
#pragma unroll
    for (int i = 0; i < 16; i++) {
        int c = c0 + i; float acc = 0.f;
        for (int k = 0; k < 64; k++) acc += qs[qr][k] * ks[c][k];
        tmp[i] = acc * 0.125f;
    }
    __syncthreads();
#pragma unroll
    for (int i = 0; i < 16; i++) sc[qr][c0 + i] = tmp[i];
#pragma unroll
    for (int i = 0; i < 16; i++) {
        int e = t + i * 256; int s = e >> 6, d = e & 63;
        ks[s][d] = b2f(QKV[(size_t)(b * SS + s) * 768 + 512 + h * 64 + d]);
    }
    __syncthreads();
    if (t < 64) {
        float mx = -1e30f;
        for (int c = 0; c < 64; c++) mx = fmaxf(mx, sc[t][c]);
        float sum = 0.f;
        for (int c = 0; c < 64; c++) { float e = expf(sc[t][c] - mx); sc[t][c] = e; sum += e; }
        float inv = 1.f / sum;
        for (int c = 0; c < 64; c++) sc[t][c] *= inv;
    }
    __syncthreads();
#pragma unroll
    for (int i = 0; i < 16; i++) {
        int d = c0 + i; float acc = 0.f;
        for (int k = 0; k < 64; k++) acc += sc[qr][k] * ks[k][d];
        O[(size_t)(b * SS + qr) * WW + h * 64 + d] = f2b(acc);
    }
}

// final head: mean over S (bf16 in) then [256]x[256,3] matvec + bias (fp32)
__global__ __launch_bounds__(256) void headk(
    const short* __restrict__ h, const float* __restrict__ ow,
    const float* __restrict__ ob, float* __restrict__ out)
{
    int b = blockIdx.x, t = threadIdx.x;
    float acc = 0.f;
    for (int s = 0; s < SS; s++) acc += b2f(h[((size_t)(b * SS + s)) * WW + t]);
    __shared__ float mean[256];
    mean[t] = acc * (1.f / 64.f);
    __syncthreads();
    if (t < 3) {
        float o = ob[t];
        for (int w = 0; w < WW; w++) o += mean[w] * ow[w * 3 + t];
        out[b * 3 + t] = o;
    }
}

// ---------------------------------------------------------------------------
#define GEMM_BF(TMv,TNv,WMv,WNv, A,Bt,bias,C,M,N,K,relu) \
  gemm_mfma<TMv,TNv,WMv,WNv,true><<<dim3((N)/(TNv),(M)/(TMv)),256,0,stream>>>((A),(Bt),(bias),nullptr,nullptr,(C),(M),(N),(K),(relu))
#define GEMM_F(TMv,TNv,WMv,WNv, A,Bt,bias,res,C,M,N,K,relu) \
  gemm_mfma<TMv,TNv,WMv,WNv,false><<<dim3((N)/(TNv),(M)/(TMv)),256,0,stream>>>((A),(Bt),(bias),(res),(C),nullptr,(M),(N),(K),(relu))

extern "C" void kernel_launch(void* const* d_in, const int* in_sizes, int n_in,
                              void* d_out, int out_size, void* d_ws, size_t ws_size,
                              hipStream_t stream)
{
    const float* rgb_feat   = (const float*)d_in[0];
    const float* ray_diff   = (const float*)d_in[1];
    const int*   maskp      = (const int*)d_in[2];
    const float* pts        = (const float*)d_in[3];
    const float* ray_d      = (const float*)d_in[4];
    const float* rgbfeat_w1 = (const float*)d_in[5];
    const float* rgbfeat_b1 = (const float*)d_in[6];
    const float* rgbfeat_w2 = (const float*)d_in[7];
    const float* rgbfeat_b2 = (const float*)d_in[8];
    const float* c_ln_g = (const float*)d_in[9];
    const float* c_ln_b = (const float*)d_in[10];
    const float* c_qw   = (const float*)d_in[11];
    const float* c_kw   = (const float*)d_in[12];
    const float* c_vw   = (const float*)d_in[13];
    const float* c_pw1  = (const float*)d_in[14];
    const float* c_pb1  = (const float*)d_in[15];
    const float* c_pw2  = (const float*)d_in[16];
    const float* c_pb2  = (const float*)d_in[17];
    const float* c_aw1  = (const float*)d_in[18];
    const float* c_ab1  = (const float*)d_in[19];
    const float* c_aw2  = (const float*)d_in[20];
    const float* c_ab2  = (const float*)d_in[21];
    const float* c_ow   = (const float*)d_in[22];
    const float* c_ob   = (const float*)d_in[23];
    const float* c_fg   = (const float*)d_in[24];
    const float* c_fb   = (const float*)d_in[25];
    const float* c_fw1  = (const float*)d_in[26];
    const float* c_fb1  = (const float*)d_in[27];
    const float* c_fw2  = (const float*)d_in[28];
    const float* c_fb2  = (const float*)d_in[29];
    const float* s_ln_g = (const float*)d_in[30];
    const float* s_ln_b = (const float*)d_in[31];
    const float* s_qw   = (const float*)d_in[32];
    const float* s_kw   = (const float*)d_in[33];
    const float* s_vw   = (const float*)d_in[34];
    const float* s_ow   = (const float*)d_in[35];
    const float* s_ob   = (const float*)d_in[36];
    const float* s_fg   = (const float*)d_in[37];
    const float* s_fb   = (const float*)d_in[38];
    const float* s_fw1  = (const float*)d_in[39];
    const float* s_fb1  = (const float*)d_in[40];
    const float* s_fw2  = (const float*)d_in[41];
    const float* s_fb2  = (const float*)d_in[42];
    const float* q_w1   = (const float*)d_in[43];
    const float* q_b1   = (const float*)d_in[44];
    const float* q_w2   = (const float*)d_in[45];
    const float* q_b2   = (const float*)d_in[46];
    const float* norm_g = (const float*)d_in[47];
    const float* norm_b = (const float*)d_in[48];
    const float* out_w  = (const float*)d_in[49];
    const float* out_b  = (const float*)d_in[50];
    float* out = (float*)d_out;

    // ---- workspace carve (256B aligned) ----
    char* p = (char*)d_ws;
    auto alloc = [&](size_t bytes) { char* r = p; p += (bytes + 255) & ~(size_t)255; return r; };
    short* rgbf  = (short*)alloc((size_t)BSV * 256 * 2);
    short* a_in  = (short*)alloc((size_t)BSV * 256 * 2);
    short* kv    = (short*)alloc((size_t)BSV * 512 * 2);   // also a_out fp32 alias
    float* a_out = (float*)kv;
    short* vpos  = (short*)alloc((size_t)BSV * 256 * 2);
    short* ph    = (short*)alloc((size_t)BSV * 32 * 2);
    short* obb   = (short*)alloc((size_t)BS * 256 * 2);
    short* xq    = (short*)alloc((size_t)BS * 256 * 2);
    short* hb    = (short*)alloc((size_t)BS * 256 * 2);
    short* ffh   = (short*)alloc((size_t)BS * 1024 * 2);
    short* catb  = (short*)alloc((size_t)BS * 384 * 2);
    short* qkv   = (short*)alloc((size_t)BS * 768 * 2);    // also rgbp alias (32768*64 bf16)
    short* rgbp  = qkv;
    float* qf    = (float*)alloc((size_t)BS * 256 * 4);
    float* fq    = (float*)alloc((size_t)BS * 256 * 4);
    float* ipts  = (float*)alloc((size_t)BS * 63 * 4);
    float* ivw   = (float*)alloc((size_t)BB * 27 * 4);
    // weight buffers (bf16, transposed [N,Kpad])
    short* w1T   = (short*)alloc(256 * 64 * 2);
    short* w2T   = (short*)alloc(256 * 256 * 2);
    short* qwT   = (short*)alloc((size_t)DD * 256 * 256 * 2);
    short* kvwT  = (short*)alloc((size_t)DD * 512 * 256 * 2);
    short* aw1T  = (short*)alloc((size_t)DD * 32 * 256 * 2);
    short* aw2T  = (short*)alloc((size_t)DD * 256 * 32 * 2);
    short* owT   = (short*)alloc((size_t)DD * 256 * 256 * 2);
    short* fw1T  = (short*)alloc((size_t)DD * 1024 * 256 * 2);
    short* fw2T  = (short*)alloc((size_t)DD * 256 * 1024 * 2);
    short* sqkvT = (short*)alloc((size_t)DD * 768 * 256 * 2);
    short* sowT  = (short*)alloc((size_t)DD * 256 * 256 * 2);
    short* sfw1T = (short*)alloc((size_t)DD * 1024 * 256 * 2);
    short* sfw2T = (short*)alloc((size_t)DD * 256 * 1024 * 2);
    short* qw1T  = (short*)alloc((size_t)4 * 256 * 384 * 2);
    short* qw2T  = (short*)alloc((size_t)4 * 256 * 256 * 2);

    // ---- weight conversion (transpose fp32 -> bf16 [N,Kpad]) ----
    dim3 wb(32, 8);
    wconv<<<dim3(8, 2, 1), wb, 0, stream>>>(rgbfeat_w1, w1T, 35, 256, 64, 0, 0);
    wconv<<<dim3(8, 8, 1), wb, 0, stream>>>(rgbfeat_w2, w2T, 256, 256, 256, 0, 0);
    wconv<<<dim3(8, 8, DD), wb, 0, stream>>>(c_qw, qwT, 256, 256, 256, 65536, 65536);
    wconv<<<dim3(8, 8, DD), wb, 0, stream>>>(c_kw, kvwT, 256, 256, 256, 65536, 131072);
    wconv<<<dim3(8, 8, DD), wb, 0, stream>>>(c_vw, kvwT + 65536, 256, 256, 256, 65536, 131072);
    wconv<<<dim3(1, 8, DD), wb, 0, stream>>>(c_aw1, aw1T, 256, 32, 256, 8192, 8192);
    wconv<<<dim3(8, 1, DD), wb, 0, stream>>>(c_aw2, aw2T, 32, 256, 32, 8192, 8192);
    wconv<<<dim3(8, 8, DD), wb, 0, stream>>>(c_ow, owT, 256, 256, 256, 65536, 65536);
    wconv<<<dim3(32, 8, DD), wb, 0, stream>>>(c_fw1, fw1T, 256, 1024, 256, 262144, 262144);
    wconv<<<dim3(8, 32, DD), wb, 0, stream>>>(c_fw2, fw2T, 1024, 256, 1024, 262144, 262144);
    wconv<<<dim3(8, 8, DD), wb, 0, stream>>>(s_qw, sqkvT, 256, 256, 256, 65536, 196608);
    wconv<<<dim3(8, 8, DD), wb, 0, stream>>>(s_kw, sqkvT + 65536, 256, 256, 256, 65536, 196608);
    wconv<<<dim3(8, 8, DD), wb, 0, stream>>>(s_vw, sqkvT + 131072, 256, 256, 256, 65536, 196608);
    wconv<<<dim3(8, 8, DD), wb, 0, stream>>>(s_ow, sowT, 256, 256, 256, 65536, 65536);
    wconv<<<dim3(32, 8, DD), wb, 0, stream>>>(s_fw1, sfw1T, 256, 1024, 256, 262144, 262144);
    wconv<<<dim3(8, 32, DD), wb, 0, stream>>>(s_fw2, sfw2T, 1024, 256, 1024, 262144, 262144);
    wconv<<<dim3(8, 12, 4), wb, 0, stream>>>(q_w1, qw1T, 346, 256, 384, 88576, 98304);
    wconv<<<dim3(8, 8, 4), wb, 0, stream>>>(q_w2, qw2T, 256, 256, 256, 65536, 65536);

    // ---- preamble ----
    penc_pts<<<(BS + 255) / 256, 256, 0, stream>>>(pts, ipts);
    penc_views<<<1, 64, 0, stream>>>(ray_d, ivw);
    rgbconv<<<(BSV * 64) / 256, 256, 0, stream>>>(rgb_feat, rgbp);
    GEMM_BF(128, 128, 64, 64, rgbp, w1T, rgbfeat_b1, a_in, BSV, 256, 64, 1);
    GEMM_BF(128, 128, 64, 64, a_in, w2T, rgbfeat_b2, rgbf, BSV, 256, 256, 0);
    vmax<<<BS, 256, 0, stream>>>(rgbf, fq);

    for (int i = 0; i < DD; i++) {
        int j = i >> 1;
        // ---- cross transformer ----
        lnormB<<<BS, 256, 0, stream>>>(fq, c_ln_g + i * WW, c_ln_b + i * WW, xq, 1e-6f);
        GEMM_F(64, 64, 32, 32, xq, qwT + (size_t)i * 65536, nullptr, nullptr, qf, BS, 256, 256, 0);
        GEMM_BF(128, 128, 64, 64, rgbf, kvwT + (size_t)i * 131072, nullptr, kv, BSV, 512, 256, 0);
        posprep<<<BSV, 256, 0, stream>>>(ray_diff, c_pw1 + i * 128, c_pb1 + i * 32,
                                         c_pw2 + i * 8192, c_pb2 + i * 256, kv, qf, a_in, vpos);
        GEMM_BF(128, 32, 32, 32, a_in, aw1T + (size_t)i * 8192, c_ab1 + i * 32, ph, BSV, 32, 256, 1);
        GEMM_F(128, 128, 64, 64, ph, aw2T + (size_t)i * 8192, c_ab2 + i * 256, nullptr, a_out, BSV, 256, 32, 0);
        smax<<<BS, 256, 0, stream>>>(a_out, vpos, maskp, obb);
        GEMM_F(64, 64, 32, 32, obb, owT + (size_t)i * 65536, c_ob + i * 256, fq, fq, BS, 256, 256, 0);
        lnormB<<<BS, 256, 0, stream>>>(fq, c_fg + i * WW, c_fb + i * WW, hb, 1e-6f);
        GEMM_BF(128, 128, 64, 64, hb, fw1T + (size_t)i * 262144, c_fb1 + i * 1024, ffh, BS, 1024, 256, 1);
        GEMM_F(64, 64, 32, 32, ffh, fw2T + (size_t)i * 262144, c_fb2 + i * 256, fq, fq, BS, 256, 1024, 0);

        // ---- q_fc on even layers ----
        if ((i & 1) == 0) {
            catk<<<(BS * 384) / 256, 256, 0, stream>>>(fq, ipts, ivw, catb);
            GEMM_BF(64, 64, 32, 32, catb, qw1T + (size_t)j * 98304, q_b1 + j * 256, hb, BS, 256, 384, 1);
            GEMM_F(64, 64, 32, 32, hb, qw2T + (size_t)j * 65536, q_b2 + j * 256, nullptr, fq, BS, 256, 256, 0);
        }

        // ---- self transformer ----
        lnormB<<<BS, 256, 0, stream>>>(fq, s_ln_g + i * WW, s_ln_b + i * WW, xq, 1e-6f);
        GEMM_BF(64, 64, 32, 32, xq, sqkvT + (size_t)i * 196608, nullptr, qkv, BS, 768, 256, 0);
        attnk<<<BB * 4, 256, 0, stream>>>(qkv, obb);
        GEMM_F(64, 64, 32, 32, obb, sowT + (size_t)i * 65536, s_ob + i * 256, fq, fq, BS, 256, 256, 0);
        lnormB<<<BS, 256, 0, stream>>>(fq, s_fg + i * WW, s_fb + i * WW, hb, 1e-6f);
        GEMM_BF(128, 128, 64, 64, hb, sfw1T + (size_t)i * 262144, s_fb1 + i * 1024, ffh, BS, 1024, 256, 1);
        GEMM_F(64, 64, 32, 32, ffh, sfw2T + (size_t)i * 262144, s_fb2 + i * 256, fq, fq, BS, 256, 1024, 0);
    }

    // ---- final norm + head ----
    lnormB<<<BS, 256, 0, stream>>>(fq, norm_g, norm_b, hb, 1e-5f);
    headk<<<BB, 256, 0, stream>>>(hb, out_w, out_b, out);
}

// Round 3
// 2183.226 us; speedup vs baseline: 5.2378x; 1.2169x over previous
//
#include <hip/hip_runtime.h>
#include <hip/hip_bf16.h>
#include <math.h>

#define BB 64
#define SS 64
#define VV 8
#define WW 256
#define DD 8
#define BS (BB*SS)        // 4096
#define BSV (BB*SS*VV)    // 32768

typedef __attribute__((ext_vector_type(8))) short s8v;
typedef __attribute__((ext_vector_type(4))) float f4v;

__device__ __forceinline__ short f2b(float f) {
    __hip_bfloat16 h = __float2bfloat16(f);
    return *reinterpret_cast<short*>(&h);
}
__device__ __forceinline__ float b2f(short s) {
    __hip_bfloat16 h = *reinterpret_cast<__hip_bfloat16*>(&s);
    return __bfloat162float(h);
}

// ---------------------------------------------------------------------------
// bf16 MFMA GEMM: C[M,N] = act(A[M,K] @ B[K,N] + bias) (+ res)
// A: bf16 [M,K] row-major (contiguous, lda=K). Bt: bf16 [N,K] pre-transposed.
// C written with leading dim ldc. 256 threads (4 waves), BK=32, 16x16x32 MFMA.
// ---------------------------------------------------------------------------
template<int TM, int TN, int WM, int WN, bool OUTBF>
__global__ __launch_bounds__(256) void gemm_mfma(
    const short* __restrict__ A, const short* __restrict__ Bt,
    const float* __restrict__ bias, const float* __restrict__ res,
    float* __restrict__ Cf, short* __restrict__ Cb,
    int M, int N, int K, int ldc, int relu)
{
    constexpr int MT  = WM / 16;
    constexpr int NT  = WN / 16;
    constexpr int RWN = TN / WN;
    __shared__ __align__(16) short As[TM * 32];
    __shared__ __align__(16) short Bs[TN * 32];
    int tid = threadIdx.x;
    int m0 = blockIdx.y * TM, n0 = blockIdx.x * TN;
    int lane = tid & 63, w = tid >> 6;
    int lm = lane & 15, lq = lane >> 4;
    int wm = (w / RWN) * WM, wn = (w % RWN) * WN;
    f4v acc[MT][NT];
#pragma unroll
    for (int i = 0; i < MT; i++)
#pragma unroll
        for (int j = 0; j < NT; j++) acc[i][j] = (f4v){0.f, 0.f, 0.f, 0.f};

    for (int k0 = 0; k0 < K; k0 += 32) {
        for (int c = tid; c < TM * 4; c += 256) {
            int r = c >> 2, kc = (c & 3) << 3;
            *(s8v*)&As[(r << 5) + kc] = *(const s8v*)&A[(size_t)(m0 + r) * K + k0 + kc];
        }
        for (int c = tid; c < TN * 4; c += 256) {
            int r = c >> 2, kc = (c & 3) << 3;
            *(s8v*)&Bs[(r << 5) + kc] = *(const s8v*)&Bt[(size_t)(n0 + r) * K + k0 + kc];
        }
        __syncthreads();
        s8v af[MT], bfv[NT];
#pragma unroll
        for (int i = 0; i < MT; i++)
            af[i] = *(const s8v*)&As[(wm + i * 16 + lm) * 32 + lq * 8];
#pragma unroll
        for (int j = 0; j < NT; j++)
            bfv[j] = *(const s8v*)&Bs[(wn + j * 16 + lm) * 32 + lq * 8];
#pragma unroll
        for (int i = 0; i < MT; i++)
#pragma unroll
            for (int j = 0; j < NT; j++)
                acc[i][j] = __builtin_amdgcn_mfma_f32_16x16x32_bf16(af[i], bfv[j], acc[i][j], 0, 0, 0);
        __syncthreads();
    }
#pragma unroll
    for (int i = 0; i < MT; i++) {
        int row = m0 + wm + i * 16 + lq * 4;
#pragma unroll
        for (int j = 0; j < NT; j++) {
            int col = n0 + wn + j * 16 + lm;
            float bv = bias ? bias[col] : 0.f;
#pragma unroll
            for (int r = 0; r < 4; r++) {
                float v = acc[i][j][r] + bv;
                if (relu) v = fmaxf(v, 0.f);
                size_t idx = (size_t)(row + r) * ldc + col;
                if (OUTBF) {
                    Cb[idx] = f2b(v);
                } else {
                    if (res) v += res[idx];
                    Cf[idx] = v;
                }
            }
        }
    }
}

// ---------------------------------------------------------------------------
// Weight convert+transpose: W fp32 [K,N] (per-z stride zi) -> Wt bf16 [N,Kpad]
// (per-z stride zo), zero-padded for k >= K. Block (32,8).
// ---------------------------------------------------------------------------
__global__ void wconv(const float* __restrict__ W, short* __restrict__ Wt,
                      int K, int N, int Kpad, int zi, size_t zo)
{
    __shared__ float t[32][33];
    int z = blockIdx.z;
    W  += (size_t)z * zi;
    Wt += (size_t)z * zo;
    int n0 = blockIdx.x * 32, k0 = blockIdx.y * 32;
    int tx = threadIdx.x, ty = threadIdx.y;
#pragma unroll
    for (int i = 0; i < 4; i++) {
        int k = k0 + ty + i * 8;
        t[ty + i * 8][tx] = (k < K) ? W[(size_t)k * N + n0 + tx] : 0.f;
    }
    __syncthreads();
#pragma unroll
    for (int i = 0; i < 4; i++) {
        int n = n0 + ty + i * 8;
        Wt[(size_t)n * Kpad + k0 + tx] = f2b(t[tx][ty + i * 8]);
    }
}

// rgb_feat fp32 [32768,35] -> bf16 [32768,64] zero-padded
__global__ void rgbconv(const float* __restrict__ x, short* __restrict__ o)
{
    int idx = blockIdx.x * 256 + threadIdx.x;
    int row = idx >> 6, col = idx & 63;
    o[idx] = f2b(col < 35 ? x[row * 35 + col] : 0.f);
}

// LayerNorm over 256, fp32 in -> bf16 out
__global__ __launch_bounds__(256) void lnormB(
    const float* __restrict__ in, const float* __restrict__ g,
    const float* __restrict__ b, short* __restrict__ out, float eps)
{
    int row = blockIdx.x, t = threadIdx.x;
    float x = in[(size_t)row * WW + t];
    __shared__ float red[256];
    red[t] = x;
    __syncthreads();
    for (int s = 128; s > 0; s >>= 1) { if (t < s) red[t] += red[t + s]; __syncthreads(); }
    float m = red[0] * (1.f / 256.f);
    __syncthreads();
    float d = x - m;
    red[t] = d * d;
    __syncthreads();
    for (int s = 128; s > 0; s >>= 1) { if (t < s) red[t] += red[t + s]; __syncthreads(); }
    float var = red[0] * (1.f / 256.f);
    out[(size_t)row * WW + t] = f2b(d / sqrtf(var + eps) * g[t] + b[t]);
}

__global__ void penc_pts(const float* __restrict__ pts, float* __restrict__ out)
{
    int bs = blockIdx.x * blockDim.x + threadIdx.x;
    if (bs >= BS) return;
    float xs[3] = {pts[bs * 3], pts[bs * 3 + 1], pts[bs * 3 + 2]};
    float* o = out + (size_t)bs * 63;
    o[0] = xs[0]; o[1] = xs[1]; o[2] = xs[2];
    for (int d = 0; d < 3; d++) {
        float f = 1.f;
        for (int k = 0; k < 10; k++) {
            float ang = xs[d] * f;
            o[3 + d * 10 + k]  = sinf(ang);
            o[33 + d * 10 + k] = cosf(ang);
            f *= 2.f;
        }
    }
}

__global__ void penc_views(const float* __restrict__ ray_d, float* __restrict__ out)
{
    int b = threadIdx.x;
    if (b >= BB) return;
    float x = ray_d[b * 3], y = ray_d[b * 3 + 1], z = ray_d[b * 3 + 2];
    float inv = 1.f / sqrtf(x * x + y * y + z * z);
    float v[3] = {x * inv, y * inv, z * inv};
    float* o = out + (size_t)b * 27;
    o[0] = v[0]; o[1] = v[1]; o[2] = v[2];
    for (int d = 0; d < 3; d++) {
        float f = 1.f;
        for (int k = 0; k < 4; k++) {
            float ang = v[d] * f;
            o[3 + d * 4 + k]  = sinf(ang);
            o[15 + d * 4 + k] = cosf(ang);
            f *= 2.f;
        }
    }
}

// fq[bs,w] = max_v rgbfA[bs,v,w] (stride 288, cols 0..255)
__global__ void vmax(const short* __restrict__ rgbfA, float* __restrict__ fq)
{
    int idx = blockIdx.x * 256 + threadIdx.x;
    int bs = idx >> 8, w = idx & 255;
    float m = -1e30f;
    for (int v = 0; v < VV; v++) m = fmaxf(m, b2f(rgbfA[((size_t)(bs * VV + v)) * 288 + w]));
    fq[idx] = m;
}

// h_i = relu(ray_diff @ pw1 + pb1) -> rgbfA[:, 256..287] (bf16)
__global__ void hfc(const float* __restrict__ rdiff, const float* __restrict__ pw1,
                    const float* __restrict__ pb1, short* __restrict__ rgbfA)
{
    int idx = blockIdx.x * 256 + threadIdx.x;   // BSV*32
    int row = idx >> 5, t = idx & 31;
    float a = pb1[t];
    for (int c = 0; c < 4; c++) a += rdiff[row * 4 + c] * pw1[c * 32 + t];
    rgbfA[(size_t)row * 288 + 256 + t] = f2b(fmaxf(a, 0.f));
}

// a_in = bf16(kpos - q) ; kpos = kv[row][0..255], q broadcast over V
__global__ void aprep2(const short* __restrict__ kv, const float* __restrict__ q,
                       short* __restrict__ a_in)
{
    int idx = blockIdx.x * 256 + threadIdx.x;   // BSV*256
    int t = idx & 255, row = idx >> 8, bs = row >> 3;
    a_in[idx] = f2b(b2f(kv[(size_t)row * 512 + t]) - q[(size_t)bs * 256 + t]);
}

// masked softmax over V + weighted sum; a fp32 [BSV,256], vpos = kv[...,256..511]
__global__ __launch_bounds__(256) void smax(
    const float* __restrict__ a, const short* __restrict__ kv,
    const int* __restrict__ mask, short* __restrict__ o)
{
    int bs = blockIdx.x, w = threadIdx.x;
    __shared__ int m[VV];
    if (w < VV) m[w] = mask[bs * VV + w];
    __syncthreads();
    float x[VV]; float mx = -1e30f;
    for (int v = 0; v < VV; v++) {
        float t = a[((size_t)(bs * VV + v)) * WW + w];
        t = (m[v] == 0) ? -1e9f : t;
        x[v] = t; mx = fmaxf(mx, t);
    }
    float s = 0.f;
    for (int v = 0; v < VV; v++) { x[v] = expf(x[v] - mx); s += x[v]; }
    float inv = 1.f / s;
    float acc = 0.f;
    for (int v = 0; v < VV; v++)
        acc += x[v] * inv * b2f(kv[((size_t)(bs * VV + v)) * 512 + 256 + w]);
    o[(size_t)bs * WW + w] = f2b(acc);
}

// cat bf16 [4096,384] = [fq(256) | ipts(63) | ivw(27) | zeros(38)]
__global__ void catk(const float* __restrict__ fq, const float* __restrict__ ipts,
                     const float* __restrict__ ivw, short* __restrict__ cat)
{
    int idx = blockIdx.x * 256 + threadIdx.x;
    int bs = idx / 384, j = idx - bs * 384;
    float v;
    if (j < 256)      v = fq[(size_t)bs * WW + j];
    else if (j < 319) v = ipts[bs * 63 + (j - 256)];
    else if (j < 346) v = ivw[(bs >> 6) * 27 + (j - 319)];
    else              v = 0.f;
    cat[idx] = f2b(v);
}

// ---------------------------------------------------------------------------
// MFMA self-attention: one wave per (b,h). QKV packed bf16 [4096,768].
// QK^T and PV via mfma_f32_16x16x32_bf16; softmax via quad shuffles;
// P goes C-layout -> LDS -> A-layout; V transposed in LDS for B-frags.
// ---------------------------------------------------------------------------
__global__ __launch_bounds__(64) void attn_mfma(
    const short* __restrict__ QKV, short* __restrict__ O)
{
    __shared__ __align__(16) short P[64 * 72];   // padded stride 72 (144B)
    __shared__ __align__(16) short Vt[64 * 72];
    int blk = blockIdx.x;
    int b = blk >> 2, h = blk & 3, lane = threadIdx.x;
    int lm = lane & 15, lq = lane >> 4;
    const short* base = QKV + (size_t)b * 64 * 768 + h * 64;

    // V transpose into LDS: lane owns row s=lane
    {
        const short* vrow = base + 512 + (size_t)lane * 768;
#pragma unroll
        for (int c = 0; c < 8; c++) {
            s8v v = *(const s8v*)&vrow[c * 8];
#pragma unroll
            for (int j = 0; j < 8; j++)
                Vt[(c * 8 + j) * 72 + lane] = v[j];
        }
    }
    // Q,K fragments (A/B layout: [row=lane&15][k=quad*8..])
    s8v qf[4][2], kf[4][2];
#pragma unroll
    for (int i = 0; i < 4; i++)
#pragma unroll
        for (int c = 0; c < 2; c++) {
            qf[i][c] = *(const s8v*)&base[(size_t)(i * 16 + lm) * 768 + c * 32 + lq * 8];
            kf[i][c] = *(const s8v*)&base[(size_t)(i * 16 + lm) * 768 + 256 + c * 32 + lq * 8];
        }
    f4v acc[4][4];
#pragma unroll
    for (int i = 0; i < 4; i++)
#pragma unroll
        for (int j = 0; j < 4; j++) acc[i][j] = (f4v){0.f, 0.f, 0.f, 0.f};
#pragma unroll
    for (int c = 0; c < 2; c++)
#pragma unroll
        for (int i = 0; i < 4; i++)
#pragma unroll
            for (int j = 0; j < 4; j++)
                acc[i][j] = __builtin_amdgcn_mfma_f32_16x16x32_bf16(qf[i][c], kf[j][c], acc[i][j], 0, 0, 0);

    // scale + row softmax; rows: i*16 + lq*4 + r; cols: j*16 + lm
#pragma unroll
    for (int i = 0; i < 4; i++) {
#pragma unroll
        for (int r = 0; r < 4; r++) {
            float lv[4];
#pragma unroll
            for (int j = 0; j < 4; j++) lv[j] = acc[i][j][r] * 0.125f;
            float mx = fmaxf(fmaxf(lv[0], lv[1]), fmaxf(lv[2], lv[3]));
            for (int d = 1; d < 16; d <<= 1) mx = fmaxf(mx, __shfl_xor(mx, d));
            float sum = 0.f;
#pragma unroll
            for (int j = 0; j < 4; j++) { lv[j] = expf(lv[j] - mx); sum += lv[j]; }
            for (int d = 1; d < 16; d <<= 1) sum += __shfl_xor(sum, d);
            float inv = 1.f / sum;
            int row = i * 16 + lq * 4 + r;
#pragma unroll
            for (int j = 0; j < 4; j++)
                P[row * 72 + j * 16 + lm] = f2b(lv[j] * inv);
        }
    }
    __syncthreads();
    // PV: A-frags of P, B-frags of V^T (both contiguous ds_read_b128)
    s8v af[4][2], bf[4][2];
#pragma unroll
    for (int i = 0; i < 4; i++)
#pragma unroll
        for (int c = 0; c < 2; c++) {
            af[i][c] = *(const s8v*)&P[(i * 16 + lm) * 72 + c * 32 + lq * 8];
            bf[i][c] = *(const s8v*)&Vt[(i * 16 + lm) * 72 + c * 32 + lq * 8];
        }
    f4v o2[4][4];
#pragma unroll
    for (int i = 0; i < 4; i++)
#pragma unroll
        for (int j = 0; j < 4; j++) o2[i][j] = (f4v){0.f, 0.f, 0.f, 0.f};
#pragma unroll
    for (int c = 0; c < 2; c++)
#pragma unroll
        for (int i = 0; i < 4; i++)
#pragma unroll
            for (int j = 0; j < 4; j++)
                o2[i][j] = __builtin_amdgcn_mfma_f32_16x16x32_bf16(af[i][c], bf[j][c], o2[i][j], 0, 0, 0);
#pragma unroll
    for (int i = 0; i < 4; i++)
#pragma unroll
        for (int j = 0; j < 4; j++)
#pragma unroll
            for (int r = 0; r < 4; r++) {
                int s = i * 16 + lq * 4 + r, d = j * 16 + lm;
                O[(size_t)(b * 64 + s) * 256 + h * 64 + d] = f2b(o2[i][j][r]);
            }
}

// final head: mean over S (bf16 in) then [256]x[256,3] matvec + bias (fp32)
__global__ __launch_bounds__(256) void headk(
    const short* __restrict__ h, const float* __restrict__ ow,
    const float* __restrict__ ob, float* __restrict__ out)
{
    int b = blockIdx.x, t = threadIdx.x;
    float acc = 0.f;
    for (int s = 0; s < SS; s++) acc += b2f(h[((size_t)(b * SS + s)) * WW + t]);
    __shared__ float mean[256];
    mean[t] = acc * (1.f / 64.f);
    __syncthreads();
    if (t < 3) {
        float o = ob[t];
        for (int w = 0; w < WW; w++) o += mean[w] * ow[w * 3 + t];
        out[b * 3 + t] = o;
    }
}

// ---------------------------------------------------------------------------
#define GEMM_BF(TMv,TNv,WMv,WNv, A,Bt,bias,C,M,N,K,ldc,relu) \
  gemm_mfma<TMv,TNv,WMv,WNv,true><<<dim3((N)/(TNv),(M)/(TMv)),256,0,stream>>>((A),(Bt),(bias),nullptr,nullptr,(C),(M),(N),(K),(ldc),(relu))
#define GEMM_F(TMv,TNv,WMv,WNv, A,Bt,bias,res,C,M,N,K,relu) \
  gemm_mfma<TMv,TNv,WMv,WNv,false><<<dim3((N)/(TNv),(M)/(TMv)),256,0,stream>>>((A),(Bt),(bias),(res),(C),nullptr,(M),(N),(K),(N),(relu))

extern "C" void kernel_launch(void* const* d_in, const int* in_sizes, int n_in,
                              void* d_out, int out_size, void* d_ws, size_t ws_size,
                              hipStream_t stream)
{
    const float* rgb_feat   = (const float*)d_in[0];
    const float* ray_diff   = (const float*)d_in[1];
    const int*   maskp      = (const int*)d_in[2];
    const float* pts        = (const float*)d_in[3];
    const float* ray_d      = (const float*)d_in[4];
    const float* rgbfeat_w1 = (const float*)d_in[5];
    const float* rgbfeat_b1 = (const float*)d_in[6];
    const float* rgbfeat_w2 = (const float*)d_in[7];
    const float* rgbfeat_b2 = (const float*)d_in[8];
    const float* c_ln_g = (const float*)d_in[9];
    const float* c_ln_b = (const float*)d_in[10];
    const float* c_qw   = (const float*)d_in[11];
    const float* c_kw   = (const float*)d_in[12];
    const float* c_vw   = (const float*)d_in[13];
    const float* c_pw1  = (const float*)d_in[14];
    const float* c_pb1  = (const float*)d_in[15];
    const float* c_pw2  = (const float*)d_in[16];
    const float* c_pb2  = (const float*)d_in[17];
    const float* c_aw1  = (const float*)d_in[18];
    const float* c_ab1  = (const float*)d_in[19];
    const float* c_aw2  = (const float*)d_in[20];
    const float* c_ab2  = (const float*)d_in[21];
    const float* c_ow   = (const float*)d_in[22];
    const float* c_ob   = (const float*)d_in[23];
    const float* c_fg   = (const float*)d_in[24];
    const float* c_fb   = (const float*)d_in[25];
    const float* c_fw1  = (const float*)d_in[26];
    const float* c_fb1  = (const float*)d_in[27];
    const float* c_fw2  = (const float*)d_in[28];
    const float* c_fb2  = (const float*)d_in[29];
    const float* s_ln_g = (const float*)d_in[30];
    const float* s_ln_b = (const float*)d_in[31];
    const float* s_qw   = (const float*)d_in[32];
    const float* s_kw   = (const float*)d_in[33];
    const float* s_vw   = (const float*)d_in[34];
    const float* s_ow   = (const float*)d_in[35];
    const float* s_ob   = (const float*)d_in[36];
    const float* s_fg   = (const float*)d_in[37];
    const float* s_fb   = (const float*)d_in[38];
    const float* s_fw1  = (const float*)d_in[39];
    const float* s_fb1  = (const float*)d_in[40];
    const float* s_fw2  = (const float*)d_in[41];
    const float* s_fb2  = (const float*)d_in[42];
    const float* q_w1   = (const float*)d_in[43];
    const float* q_b1   = (const float*)d_in[44];
    const float* q_w2   = (const float*)d_in[45];
    const float* q_b2   = (const float*)d_in[46];
    const float* norm_g = (const float*)d_in[47];
    const float* norm_b = (const float*)d_in[48];
    const float* out_w  = (const float*)d_in[49];
    const float* out_b  = (const float*)d_in[50];
    float* out = (float*)d_out;

    // ---- workspace carve (256B aligned) ----
    char* p = (char*)d_ws;
    auto alloc = [&](size_t bytes) { char* r = p; p += (bytes + 255) & ~(size_t)255; return r; };
    short* rgbfA = (short*)alloc((size_t)BSV * 288 * 2);   // [rgbf(256) | h_i(32)]
    short* a_in  = (short*)alloc((size_t)BSV * 256 * 2);
    short* kv    = (short*)alloc((size_t)BSV * 512 * 2);   // [k+pos | v+pos]
    float* a_out = (float*)alloc((size_t)BSV * 256 * 4);
    short* ph    = (short*)alloc((size_t)BSV * 32 * 2);
    short* obb   = (short*)alloc((size_t)BS * 256 * 2);
    short* xq    = (short*)alloc((size_t)BS * 256 * 2);
    short* hb    = (short*)alloc((size_t)BS * 256 * 2);
    short* ffh   = (short*)alloc((size_t)BS * 1024 * 2);
    short* catb  = (short*)alloc((size_t)BS * 384 * 2);
    short* qkv   = (short*)alloc((size_t)BS * 768 * 2);    // also rgbp alias
    short* rgbp  = qkv;
    float* qf    = (float*)alloc((size_t)BS * 256 * 4);
    float* fq    = (float*)alloc((size_t)BS * 256 * 4);
    float* ipts  = (float*)alloc((size_t)BS * 63 * 4);
    float* ivw   = (float*)alloc((size_t)BB * 27 * 4);
    // weights (bf16, transposed [N,Kpad])
    short* w1T   = (short*)alloc(256 * 64 * 2);
    short* w2T   = (short*)alloc(256 * 256 * 2);
    short* qwT   = (short*)alloc((size_t)DD * 256 * 256 * 2);
    short* kvpT  = (short*)alloc((size_t)DD * 512 * 288 * 2);  // [kw|pw2 ; vw|pw2]^T
    short* aw1T  = (short*)alloc((size_t)DD * 32 * 256 * 2);
    short* aw2T  = (short*)alloc((size_t)DD * 256 * 32 * 2);
    short* owT   = (short*)alloc((size_t)DD * 256 * 256 * 2);
    short* fw1T  = (short*)alloc((size_t)DD * 1024 * 256 * 2);
    short* fw2T  = (short*)alloc((size_t)DD * 256 * 1024 * 2);
    short* sqkvT = (short*)alloc((size_t)DD * 768 * 256 * 2);
    short* sowT  = (short*)alloc((size_t)DD * 256 * 256 * 2);
    short* sfw1T = (short*)alloc((size_t)DD * 1024 * 256 * 2);
    short* sfw2T = (short*)alloc((size_t)DD * 256 * 1024 * 2);
    short* qw1T  = (short*)alloc((size_t)4 * 256 * 384 * 2);
    short* qw2T  = (short*)alloc((size_t)4 * 256 * 256 * 2);

    // ---- weight conversion ----
    dim3 wb(32, 8);
    wconv<<<dim3(8, 2, 1), wb, 0, stream>>>(rgbfeat_w1, w1T, 35, 256, 64, 0, 0);
    wconv<<<dim3(8, 8, 1), wb, 0, stream>>>(rgbfeat_w2, w2T, 256, 256, 256, 0, 0);
    wconv<<<dim3(8, 8, DD), wb, 0, stream>>>(c_qw, qwT, 256, 256, 256, 65536, 65536);
    // kv+pos combined weights: Bt [512][288]
    wconv<<<dim3(8, 8, DD), wb, 0, stream>>>(c_kw, kvpT, 256, 256, 288, 65536, 147456);
    wconv<<<dim3(8, 1, DD), wb, 0, stream>>>(c_pw2, kvpT + 256, 32, 256, 288, 8192, 147456);
    wconv<<<dim3(8, 8, DD), wb, 0, stream>>>(c_vw, kvpT + 256 * 288, 256, 256, 288, 65536, 147456);
    wconv<<<dim3(8, 1, DD), wb, 0, stream>>>(c_pw2, kvpT + 256 * 288 + 256, 32, 256, 288, 8192, 147456);
    wconv<<<dim3(1, 8, DD), wb, 0, stream>>>(c_aw1, aw1T, 256, 32, 256, 8192, 8192);
    wconv<<<dim3(8, 1, DD), wb, 0, stream>>>(c_aw2, aw2T, 32, 256, 32, 8192, 8192);
    wconv<<<dim3(8, 8, DD), wb, 0, stream>>>(c_ow, owT, 256, 256, 256, 65536, 65536);
    wconv<<<dim3(32, 8, DD), wb, 0, stream>>>(c_fw1, fw1T, 256, 1024, 256, 262144, 262144);
    wconv<<<dim3(8, 32, DD), wb, 0, stream>>>(c_fw2, fw2T, 1024, 256, 1024, 262144, 262144);
    wconv<<<dim3(8, 8, DD), wb, 0, stream>>>(s_qw, sqkvT, 256, 256, 256, 65536, 196608);
    wconv<<<dim3(8, 8, DD), wb, 0, stream>>>(s_kw, sqkvT + 65536, 256, 256, 256, 65536, 196608);
    wconv<<<dim3(8, 8, DD), wb, 0, stream>>>(s_vw, sqkvT + 131072, 256, 256, 256, 65536, 196608);
    wconv<<<dim3(8, 8, DD), wb, 0, stream>>>(s_ow, sowT, 256, 256, 256, 65536, 65536);
    wconv<<<dim3(32, 8, DD), wb, 0, stream>>>(s_fw1, sfw1T, 256, 1024, 256, 262144, 262144);
    wconv<<<dim3(8, 32, DD), wb, 0, stream>>>(s_fw2, sfw2T, 1024, 256, 1024, 262144, 262144);
    wconv<<<dim3(8, 12, 4), wb, 0, stream>>>(q_w1, qw1T, 346, 256, 384, 88576, 98304);
    wconv<<<dim3(8, 8, 4), wb, 0, stream>>>(q_w2, qw2T, 256, 256, 256, 65536, 65536);

    // ---- preamble ----
    penc_pts<<<(BS + 255) / 256, 256, 0, stream>>>(pts, ipts);
    penc_views<<<1, 64, 0, stream>>>(ray_d, ivw);
    rgbconv<<<(BSV * 64) / 256, 256, 0, stream>>>(rgb_feat, rgbp);
    GEMM_BF(128, 128, 64, 64, rgbp, w1T, rgbfeat_b1, a_in, BSV, 256, 64, 256, 1);
    GEMM_BF(128, 128, 64, 64, a_in, w2T, rgbfeat_b2, rgbfA, BSV, 256, 256, 288, 0);
    vmax<<<BS, 256, 0, stream>>>(rgbfA, fq);

    for (int i = 0; i < DD; i++) {
        int j = i >> 1;
        // ---- cross transformer ----
        lnormB<<<BS, 256, 0, stream>>>(fq, c_ln_g + i * WW, c_ln_b + i * WW, xq, 1e-6f);
        GEMM_F(64, 64, 32, 32, xq, qwT + (size_t)i * 65536, nullptr, nullptr, qf, BS, 256, 256, 0);
        hfc<<<(BSV * 32) / 256, 256, 0, stream>>>(ray_diff, c_pw1 + i * 128, c_pb1 + i * 32, rgbfA);
        GEMM_BF(128, 128, 64, 64, rgbfA, kvpT + (size_t)i * 147456, nullptr, kv, BSV, 512, 288, 512, 0);
        aprep2<<<BSV, 256, 0, stream>>>(kv, qf, a_in);
        GEMM_BF(128, 32, 32, 32, a_in, aw1T + (size_t)i * 8192, c_ab1 + i * 32, ph, BSV, 32, 256, 32, 1);
        GEMM_F(128, 128, 64, 64, ph, aw2T + (size_t)i * 8192, c_ab2 + i * 256, nullptr, a_out, BSV, 256, 32, 0);
        smax<<<BS, 256, 0, stream>>>(a_out, kv, maskp, obb);
        GEMM_F(64, 64, 32, 32, obb, owT + (size_t)i * 65536, c_ob + i * 256, fq, fq, BS, 256, 256, 0);
        lnormB<<<BS, 256, 0, stream>>>(fq, c_fg + i * WW, c_fb + i * WW, hb, 1e-6f);
        GEMM_BF(128, 128, 64, 64, hb, fw1T + (size_t)i * 262144, c_fb1 + i * 1024, ffh, BS, 1024, 256, 1024, 1);
        GEMM_F(64, 64, 32, 32, ffh, fw2T + (size_t)i * 262144, c_fb2 + i * 256, fq, fq, BS, 256, 1024, 0);

        // ---- q_fc on even layers ----
        if ((i & 1) == 0) {
            catk<<<(BS * 384) / 256, 256, 0, stream>>>(fq, ipts, ivw, catb);
            GEMM_BF(64, 64, 32, 32, catb, qw1T + (size_t)j * 98304, q_b1 + j * 256, hb, BS, 256, 384, 256, 1);
            GEMM_F(64, 64, 32, 32, hb, qw2T + (size_t)j * 65536, q_b2 + j * 256, nullptr, fq, BS, 256, 256, 0);
        }

        // ---- self transformer ----
        lnormB<<<BS, 256, 0, stream>>>(fq, s_ln_g + i * WW, s_ln_b + i * WW, xq, 1e-6f);
        GEMM_BF(64, 64, 32, 32, xq, sqkvT + (size_t)i * 196608, nullptr, qkv, BS, 768, 256, 768, 0);
        attn_mfma<<<BB * 4, 64, 0, stream>>>(qkv, obb);
        GEMM_F(64, 64, 32, 32, obb, sowT + (size_t)i * 65536, s_ob + i * 256, fq, fq, BS, 256, 256, 0);
        lnormB<<<BS, 256, 0, stream>>>(fq, s_fg + i * WW, s_fb + i * WW, hb, 1e-6f);
        GEMM_BF(128, 128, 64, 64, hb, sfw1T + (size_t)i * 262144, s_fb1 + i * 1024, ffh, BS, 1024, 256, 1024, 1);
        GEMM_F(64, 64, 32, 32, ffh, sfw2T + (size_t)i * 262144, s_fb2 + i * 256, fq, fq, BS, 256, 1024, 0);
    }

    // ---- final norm + head ----
    lnormB<<<BS, 256, 0, stream>>>(fq, norm_g, norm_b, hb, 1e-5f);
    headk<<<BB, 256, 0, stream>>>(hb, out_w, out_b, out);
}